// Round 2
// baseline (697.404 us; speedup 1.0000x reference)
//
#include <hip/hip_runtime.h>
#include <hip/hip_bf16.h>

// Problem constants (fixed by the reference):
#define E_EDGES 640000
#define DIM     128
#define N_NODES 40000

typedef __bf16 bf16x8 __attribute__((ext_vector_type(8)));
typedef float  floatx4 __attribute__((ext_vector_type(4)));

// d_ws layout (bytes):
//   [0,        32768)   Wsw      : bf16 W in B-fragment lane order (32 KB)
//   [32768,   192768)   counts   : int[40000]
//   [196608,  356612)   offsets  : int[40001]
//   [360448,  520448)   cursor   : int[40000]
//   [524288, 3084288)   sorted   : int[640000] edge ids grouped by dst
#define WS_WSW     0
#define WS_COUNTS  32768
#define WS_OFFSETS 196608
#define WS_CURSOR  360448
#define WS_SORTED  524288

// prep: init out to -inf (empty segments), zero histogram, swizzle W to bf16
// B-frag order: Wsw[((nb*4+kb)*64+lane)*8+j] = W[nb*16+(lane&15)][kb*32+(lane>>4)*8+j]
__global__ void prep_kernel(const float* __restrict__ W,
                            __bf16* __restrict__ Wsw,
                            int* __restrict__ counts,
                            int* __restrict__ out_i) {
    int tid = blockIdx.x * blockDim.x + threadIdx.x;
    if (tid < N_NODES * DIM) out_i[tid] = 0xFF800000;  // -inf
    if (tid < N_NODES) counts[tid] = 0;
    if (tid < 2048) {
        int lane = tid & 63;
        int kb   = (tid >> 6) & 3;
        int nb   = tid >> 8;
        int f    = nb * 16 + (lane & 15);
        int k0   = kb * 32 + ((lane >> 4) & 3) * 8;
        const float* wrow = W + f * DIM + k0;
        __bf16* o = Wsw + tid * 8;
#pragma unroll
        for (int j = 0; j < 8; ++j) o[j] = (__bf16)wrow[j];
    }
}

__global__ void hist_kernel(const int* __restrict__ dst, int* __restrict__ counts) {
    int e = blockIdx.x * blockDim.x + threadIdx.x;
    if (e < E_EDGES) atomicAdd(&counts[dst[e]], 1);
}

// Single-block exclusive prefix sum over 40000 counts -> offsets[40001], cursor copy.
#define SCAN_T 1024
__global__ __launch_bounds__(SCAN_T)
void scan_kernel(const int* __restrict__ counts,
                 int* __restrict__ offsets,
                 int* __restrict__ cursor) {
    __shared__ int sm[SCAN_T];
    __shared__ int s_carry;
    int tid = threadIdx.x;
    if (tid == 0) s_carry = 0;
    __syncthreads();
    for (int base = 0; base < N_NODES; base += SCAN_T) {
        int i = base + tid;
        int x = (i < N_NODES) ? counts[i] : 0;
        sm[tid] = x;
        __syncthreads();
#pragma unroll
        for (int off = 1; off < SCAN_T; off <<= 1) {
            int v = (tid >= off) ? sm[tid - off] : 0;
            __syncthreads();
            sm[tid] += v;
            __syncthreads();
        }
        int carry = s_carry;                 // read before next write (barrier below)
        int incl  = sm[tid];
        if (i < N_NODES) {
            int excl = incl - x + carry;
            offsets[i] = excl;
            cursor[i]  = excl;
        }
        __syncthreads();
        if (tid == SCAN_T - 1) s_carry = carry + incl;
        __syncthreads();
    }
    if (tid == 0) offsets[N_NODES] = s_carry;  // == E_EDGES
}

__global__ void scatter_kernel(const int* __restrict__ dst,
                               int* __restrict__ cursor,
                               int* __restrict__ sorted) {
    int e = blockIdx.x * blockDim.x + threadIdx.x;
    if (e < E_EDGES) {
        int pos = atomicAdd(&cursor[dst[e]], 1);
        sorted[pos] = e;
    }
}

// One wave per node: segment-max over the node's edges, no atomics.
// Per 16-edge tile: gather A rows (duplicate last edge as padding — max-idempotent),
// 4 kb x 8 nb mfma_f32_16x16x32_bf16, fold C-regs into per-col running max.
// C/D map: col = nb*16 + (lane&15), row = (lane>>4)*4 + reg.
// Cross-row reduce: in-lane over 4 regs, then shfl_xor 16/32 across q-groups.
__global__ __launch_bounds__(256)
void gemm_csr_kernel(const float* __restrict__ src,
                     const __bf16* __restrict__ Wsw,
                     const float* __restrict__ bias,
                     const int* __restrict__ offsets,
                     const int* __restrict__ sorted,
                     float* __restrict__ out) {
    const int lane = threadIdx.x & 63;
    const int wave = threadIdx.x >> 6;
    const int node = blockIdx.x * 4 + wave;
    if (node >= N_NODES) return;
    const int q = lane >> 4;
    const int n = lane & 15;

    const int s = offsets[node];
    const int e = offsets[node + 1];
    if (s == e) return;  // empty segment: out stays -inf from prep

    const bf16x8* Wf = (const bf16x8*)Wsw;

    float cmax[8];
#pragma unroll
    for (int nb = 0; nb < 8; ++nb) cmax[nb] = -3.0e38f;

    for (int t = s; t < e; t += 16) {
        int ei  = t + n;
        int eid = sorted[ei < e ? ei : e - 1];
        const float* arow = src + (size_t)eid * DIM + q * 8;

        floatx4 acc[8];
#pragma unroll
        for (int nb = 0; nb < 8; ++nb) acc[nb] = (floatx4)(0.0f);

#pragma unroll
        for (int kb = 0; kb < 4; ++kb) {
            float4 a0 = *(const float4*)(arow + kb * 32);
            float4 a1 = *(const float4*)(arow + kb * 32 + 4);
            bf16x8 af;
            af[0] = (__bf16)a0.x; af[1] = (__bf16)a0.y;
            af[2] = (__bf16)a0.z; af[3] = (__bf16)a0.w;
            af[4] = (__bf16)a1.x; af[5] = (__bf16)a1.y;
            af[6] = (__bf16)a1.z; af[7] = (__bf16)a1.w;
#pragma unroll
            for (int nb = 0; nb < 8; ++nb) {
                bf16x8 bf = Wf[(nb * 4 + kb) * 64 + lane];
                acc[nb] = __builtin_amdgcn_mfma_f32_16x16x32_bf16(af, bf, acc[nb], 0, 0, 0);
            }
        }
#pragma unroll
        for (int nb = 0; nb < 8; ++nb) {
            float m01 = acc[nb][0] > acc[nb][1] ? acc[nb][0] : acc[nb][1];
            float m23 = acc[nb][2] > acc[nb][3] ? acc[nb][2] : acc[nb][3];
            float m = m01 > m23 ? m01 : m23;
            cmax[nb] = cmax[nb] > m ? cmax[nb] : m;
        }
    }

    // reduce across the 4 q-groups (rows) and write relu(max + b)
#pragma unroll
    for (int nb = 0; nb < 8; ++nb) {
        float v = cmax[nb];
        float o = __shfl_xor(v, 16);
        v = v > o ? v : o;
        o = __shfl_xor(v, 32);
        v = v > o ? v : o;
        if (q == 0) {
            int col = nb * 16 + n;
            float r = v + bias[col];
            out[(size_t)node * DIM + col] = r > 0.0f ? r : 0.0f;
        }
    }
}

extern "C" void kernel_launch(void* const* d_in, const int* in_sizes, int n_in,
                              void* d_out, int out_size, void* d_ws, size_t ws_size,
                              hipStream_t stream) {
    const float* src  = (const float*)d_in[0];
    const float* W    = (const float*)d_in[1];
    const float* bias = (const float*)d_in[2];
    const int*   dst  = (const int*)d_in[3];

    char* ws = (char*)d_ws;
    __bf16* Wsw     = (__bf16*)(ws + WS_WSW);
    int*    counts  = (int*)(ws + WS_COUNTS);
    int*    offsets = (int*)(ws + WS_OFFSETS);
    int*    cursor  = (int*)(ws + WS_CURSOR);
    int*    sorted  = (int*)(ws + WS_SORTED);
    float*  out     = (float*)d_out;

    prep_kernel<<<(N_NODES * DIM + 255) / 256, 256, 0, stream>>>(W, Wsw, counts, (int*)d_out);
    hist_kernel<<<(E_EDGES + 255) / 256, 256, 0, stream>>>(dst, counts);
    scan_kernel<<<1, SCAN_T, 0, stream>>>(counts, offsets, cursor);
    scatter_kernel<<<(E_EDGES + 255) / 256, 256, 0, stream>>>(dst, cursor, sorted);
    gemm_csr_kernel<<<(N_NODES + 3) / 4, 256, 0, stream>>>(src, Wsw, bias, offsets, sorted, out);
}

// Round 3
// 578.896 us; speedup vs baseline: 1.2047x; 1.2047x over previous
//
#include <hip/hip_runtime.h>
#include <hip/hip_bf16.h>

// Problem constants (fixed by the reference):
#define E_EDGES 640000
#define DIM     128
#define N_NODES 40000

typedef __bf16 bf16x8 __attribute__((ext_vector_type(8)));
typedef float  floatx4 __attribute__((ext_vector_type(4)));

// d_ws layout (bytes):
//   [0,        32768)    Wsw      : bf16 W in B-fragment lane order (32 KB)
//   [32768,   192768)    counts   : int[40000]
//   [196608,  356612)    offsets  : int[40001]
//   [360448,  520448)    cursor   : int[40000]
//   [520448,  520704)    partials : int[64]
//   [524288,  3084288)   inv      : int[640000]  (fallback: 'sorted')
//   [3145728, 166985728) msg      : bf16[640000*128] permuted messages (164 MB)
#define WS_WSW      0u
#define WS_COUNTS   32768u
#define WS_OFFSETS  196608u
#define WS_CURSOR   360448u
#define WS_PARTIALS 520448u
#define WS_INV      524288u
#define WS_MSG      3145728u
#define WS_NEEDED   (WS_MSG + (size_t)E_EDGES * DIM * 2)

// ---------------- prep: out=-inf, zero hist, swizzle W to bf16 B-frag order ---
// Wsw[((nb*4+kb)*64+lane)*8+j] = W[nb*16+(lane&15)][kb*32+(lane>>4)*8+j]
__global__ void prep_kernel(const float* __restrict__ W,
                            __bf16* __restrict__ Wsw,
                            int* __restrict__ counts,
                            int* __restrict__ out_i) {
    int tid = blockIdx.x * blockDim.x + threadIdx.x;
    if (tid < N_NODES * DIM) out_i[tid] = 0xFF800000;  // -inf (empty segments)
    if (tid < N_NODES) counts[tid] = 0;
    if (tid < 2048) {
        int lane = tid & 63;
        int kb   = (tid >> 6) & 3;
        int nb   = tid >> 8;
        int f    = nb * 16 + (lane & 15);
        int k0   = kb * 32 + ((lane >> 4) & 3) * 8;
        const float* wrow = W + f * DIM + k0;
        __bf16* o = Wsw + tid * 8;
#pragma unroll
        for (int j = 0; j < 8; ++j) o[j] = (__bf16)wrow[j];
    }
}

__global__ void hist_kernel(const int* __restrict__ dst, int* __restrict__ counts) {
    int e = blockIdx.x * blockDim.x + threadIdx.x;
    if (e < E_EDGES) atomicAdd(&counts[dst[e]], 1);
}

// ---------------- hierarchical scan: 40 blocks x 1024 elems -> 40 partials ----
#define SB 256
#define SE 4
__global__ __launch_bounds__(SB)
void scan1_kernel(const int* __restrict__ counts,
                  int* __restrict__ loc,        // per-elem block-local exclusive
                  int* __restrict__ partials) {
    __shared__ int sm[SB];
    int b = blockIdx.x, tid = threadIdx.x;
    int base = b * SB * SE + tid * SE;
    int v[SE], s = 0;
#pragma unroll
    for (int j = 0; j < SE; ++j) {
        int i = base + j;
        v[j] = (i < N_NODES) ? counts[i] : 0;
        s += v[j];
    }
    sm[tid] = s;
    __syncthreads();
#pragma unroll
    for (int off = 1; off < SB; off <<= 1) {
        int t = (tid >= off) ? sm[tid - off] : 0;
        __syncthreads();
        sm[tid] += t;
        __syncthreads();
    }
    int excl = sm[tid] - s;
    if (tid == SB - 1) partials[b] = sm[tid];
    int run = excl;
#pragma unroll
    for (int j = 0; j < SE; ++j) {
        int i = base + j;
        if (i < N_NODES) loc[i] = run;
        run += v[j];
    }
}

// exclusive scan of the 40 block partials, one wave via shfl
__global__ void scan2_kernel(int* __restrict__ partials, int nblocks) {
    int lane = threadIdx.x & 63;
    int v = (lane < nblocks) ? partials[lane] : 0;
    int orig = v;
#pragma unroll
    for (int off = 1; off < 64; off <<= 1) {
        int o = __shfl_up(v, off);
        if (lane >= off) v += o;
    }
    if (lane < nblocks) partials[lane] = v - orig;
}

__global__ void scan3_kernel(int* __restrict__ offsets,   // in: loc, out: final
                             const int* __restrict__ partials,
                             int* __restrict__ cursor) {
    int i = blockIdx.x * blockDim.x + threadIdx.x;
    if (i < N_NODES) {
        int o = offsets[i] + partials[i / (SB * SE)];
        offsets[i] = o;
        cursor[i]  = o;
    }
    if (i == 0) offsets[N_NODES] = E_EDGES;
}

// ---------------- scatter: main path writes inv[e]=pos (coalesced) -----------
__global__ void scatter_inv_kernel(const int* __restrict__ dst,
                                   int* __restrict__ cursor,
                                   int* __restrict__ inv) {
    int e = blockIdx.x * blockDim.x + threadIdx.x;
    if (e < E_EDGES) inv[e] = atomicAdd(&cursor[dst[e]], 1);
}

__global__ void scatter_sorted_kernel(const int* __restrict__ dst,
                                      int* __restrict__ cursor,
                                      int* __restrict__ sorted) {
    int e = blockIdx.x * blockDim.x + threadIdx.x;
    if (e < E_EDGES) {
        int pos = atomicAdd(&cursor[dst[e]], 1);
        sorted[pos] = e;
    }
}

// ---------------- phase 1: edge-major GEMM, scatter bf16 rows to sorted pos --
// msg row layout: position p = n*8 + nb holds col = nb*16 + n  (lane-contig 16B)
// A-frag coalesced from global; C/D: col=nb*16+(lane&15), row=(lane>>4)*4+reg.
// No bias/relu here (monotone — applied once per node in phase 2).
__global__ __launch_bounds__(256)
void gemm_scatter_kernel(const float* __restrict__ src,
                         const __bf16* __restrict__ Wsw,
                         const int* __restrict__ inv,
                         __bf16* __restrict__ msg) {
    const int lane = threadIdx.x & 63;
    const int wave = threadIdx.x >> 6;
    const int q    = lane >> 4;
    const int n    = lane & 15;
    const int eb   = blockIdx.x * 64 + wave * 16;

    int pos[4];
#pragma unroll
    for (int r = 0; r < 4; ++r) pos[r] = inv[eb + q * 4 + r];

    floatx4 acc[8];
#pragma unroll
    for (int nb = 0; nb < 8; ++nb) acc[nb] = (floatx4)(0.0f);

    const float* arow = src + (size_t)(eb + n) * DIM + q * 8;
    const bf16x8* Wf = (const bf16x8*)Wsw;

#pragma unroll
    for (int kb = 0; kb < 4; ++kb) {
        float4 a0 = *(const float4*)(arow + kb * 32);
        float4 a1 = *(const float4*)(arow + kb * 32 + 4);
        bf16x8 af;
        af[0] = (__bf16)a0.x; af[1] = (__bf16)a0.y;
        af[2] = (__bf16)a0.z; af[3] = (__bf16)a0.w;
        af[4] = (__bf16)a1.x; af[5] = (__bf16)a1.y;
        af[6] = (__bf16)a1.z; af[7] = (__bf16)a1.w;
#pragma unroll
        for (int nb = 0; nb < 8; ++nb) {
            bf16x8 bf = Wf[(nb * 4 + kb) * 64 + lane];
            acc[nb] = __builtin_amdgcn_mfma_f32_16x16x32_bf16(af, bf, acc[nb], 0, 0, 0);
        }
    }

#pragma unroll
    for (int r = 0; r < 4; ++r) {
        bf16x8 o;
#pragma unroll
        for (int nb = 0; nb < 8; ++nb) o[nb] = (__bf16)acc[nb][r];
        *(bf16x8*)(msg + (size_t)pos[r] * DIM + n * 8) = o;
    }
}

// ---------------- phase 2: contiguous segment max, bias+relu, store ----------
__global__ __launch_bounds__(256)
void segmax_kernel(const __bf16* __restrict__ msg,
                   const float* __restrict__ bias,
                   const int* __restrict__ offsets,
                   float* __restrict__ out) {
    const int lane = threadIdx.x & 63;
    const int wave = threadIdx.x >> 6;
    const int node = blockIdx.x * 4 + wave;
    if (node >= N_NODES) return;
    const int rg = lane >> 4;
    const int n  = lane & 15;

    const int s = offsets[node];
    const int e = offsets[node + 1];
    if (s == e) return;  // empty: out stays -inf from prep

    float vm[8];
#pragma unroll
    for (int j = 0; j < 8; ++j) vm[j] = -3.0e38f;

    int t = s + rg;
    for (; t + 4 < e; t += 8) {  // 2-way unrolled for MLP
        bf16x8 m0 = *(const bf16x8*)(msg + (size_t)t * DIM + n * 8);
        bf16x8 m1 = *(const bf16x8*)(msg + (size_t)(t + 4) * DIM + n * 8);
#pragma unroll
        for (int j = 0; j < 8; ++j) {
            float f0 = (float)m0[j], f1 = (float)m1[j];
            float f = f0 > f1 ? f0 : f1;
            vm[j] = vm[j] > f ? vm[j] : f;
        }
    }
    if (t < e) {
        bf16x8 m0 = *(const bf16x8*)(msg + (size_t)t * DIM + n * 8);
#pragma unroll
        for (int j = 0; j < 8; ++j) {
            float f0 = (float)m0[j];
            vm[j] = vm[j] > f0 ? vm[j] : f0;
        }
    }

#pragma unroll
    for (int j = 0; j < 8; ++j) {
        float v = vm[j];
        float o = __shfl_xor(v, 16);
        v = v > o ? v : o;
        o = __shfl_xor(v, 32);
        v = v > o ? v : o;
        vm[j] = v;
    }
    if (rg == 0) {
#pragma unroll
        for (int j = 0; j < 8; ++j) {
            int col = j * 16 + n;               // p = n*8 + j  ->  col = j*16 + n
            float r = vm[j] + bias[col];
            out[(size_t)node * DIM + col] = r > 0.0f ? r : 0.0f;
        }
    }
}

// ---------------- fallback: round-2 gather kernel (ws too small) -------------
__global__ __launch_bounds__(256)
void gemm_csr_kernel(const float* __restrict__ src,
                     const __bf16* __restrict__ Wsw,
                     const float* __restrict__ bias,
                     const int* __restrict__ offsets,
                     const int* __restrict__ sorted,
                     float* __restrict__ out) {
    const int lane = threadIdx.x & 63;
    const int wave = threadIdx.x >> 6;
    const int node = blockIdx.x * 4 + wave;
    if (node >= N_NODES) return;
    const int q = lane >> 4;
    const int n = lane & 15;

    const int s = offsets[node];
    const int e = offsets[node + 1];
    if (s == e) return;

    const bf16x8* Wf = (const bf16x8*)Wsw;
    float cmax[8];
#pragma unroll
    for (int nb = 0; nb < 8; ++nb) cmax[nb] = -3.0e38f;

    for (int t = s; t < e; t += 16) {
        int ei  = t + n;
        int eid = sorted[ei < e ? ei : e - 1];
        const float* arow = src + (size_t)eid * DIM + q * 8;
        floatx4 acc[8];
#pragma unroll
        for (int nb = 0; nb < 8; ++nb) acc[nb] = (floatx4)(0.0f);
#pragma unroll
        for (int kb = 0; kb < 4; ++kb) {
            float4 a0 = *(const float4*)(arow + kb * 32);
            float4 a1 = *(const float4*)(arow + kb * 32 + 4);
            bf16x8 af;
            af[0] = (__bf16)a0.x; af[1] = (__bf16)a0.y;
            af[2] = (__bf16)a0.z; af[3] = (__bf16)a0.w;
            af[4] = (__bf16)a1.x; af[5] = (__bf16)a1.y;
            af[6] = (__bf16)a1.z; af[7] = (__bf16)a1.w;
#pragma unroll
            for (int nb = 0; nb < 8; ++nb) {
                bf16x8 bf = Wf[(nb * 4 + kb) * 64 + lane];
                acc[nb] = __builtin_amdgcn_mfma_f32_16x16x32_bf16(af, bf, acc[nb], 0, 0, 0);
            }
        }
#pragma unroll
        for (int nb = 0; nb < 8; ++nb) {
            float m01 = acc[nb][0] > acc[nb][1] ? acc[nb][0] : acc[nb][1];
            float m23 = acc[nb][2] > acc[nb][3] ? acc[nb][2] : acc[nb][3];
            float m = m01 > m23 ? m01 : m23;
            cmax[nb] = cmax[nb] > m ? cmax[nb] : m;
        }
    }
#pragma unroll
    for (int nb = 0; nb < 8; ++nb) {
        float v = cmax[nb];
        float o = __shfl_xor(v, 16);
        v = v > o ? v : o;
        o = __shfl_xor(v, 32);
        v = v > o ? v : o;
        if (q == 0) {
            int col = nb * 16 + n;
            float r = v + bias[col];
            out[(size_t)node * DIM + col] = r > 0.0f ? r : 0.0f;
        }
    }
}

extern "C" void kernel_launch(void* const* d_in, const int* in_sizes, int n_in,
                              void* d_out, int out_size, void* d_ws, size_t ws_size,
                              hipStream_t stream) {
    const float* src  = (const float*)d_in[0];
    const float* W    = (const float*)d_in[1];
    const float* bias = (const float*)d_in[2];
    const int*   dst  = (const int*)d_in[3];

    char* ws = (char*)d_ws;
    __bf16* Wsw      = (__bf16*)(ws + WS_WSW);
    int*    counts   = (int*)(ws + WS_COUNTS);
    int*    offsets  = (int*)(ws + WS_OFFSETS);
    int*    cursor   = (int*)(ws + WS_CURSOR);
    int*    partials = (int*)(ws + WS_PARTIALS);
    int*    inv      = (int*)(ws + WS_INV);     // fallback: sorted
    __bf16* msg      = (__bf16*)(ws + WS_MSG);
    float*  out      = (float*)d_out;

    const int scan_blocks = (N_NODES + SB * SE - 1) / (SB * SE);  // 40

    prep_kernel<<<(N_NODES * DIM + 255) / 256, 256, 0, stream>>>(W, Wsw, counts, (int*)d_out);
    hist_kernel<<<(E_EDGES + 255) / 256, 256, 0, stream>>>(dst, counts);
    scan1_kernel<<<scan_blocks, SB, 0, stream>>>(counts, offsets, partials);
    scan2_kernel<<<1, 64, 0, stream>>>(partials, scan_blocks);
    scan3_kernel<<<(N_NODES + 255) / 256, 256, 0, stream>>>(offsets, partials, cursor);

    if (ws_size >= WS_NEEDED) {
        scatter_inv_kernel<<<(E_EDGES + 255) / 256, 256, 0, stream>>>(dst, cursor, inv);
        gemm_scatter_kernel<<<E_EDGES / 64, 256, 0, stream>>>(src, Wsw, inv, msg);
        segmax_kernel<<<(N_NODES + 3) / 4, 256, 0, stream>>>(msg, bias, offsets, out);
    } else {
        scatter_sorted_kernel<<<(E_EDGES + 255) / 256, 256, 0, stream>>>(dst, cursor, inv);
        gemm_csr_kernel<<<(N_NODES + 3) / 4, 256, 0, stream>>>(src, Wsw, bias, offsets, inv, out);
    }
}